// Round 2
// baseline (165658.765 us; speedup 1.0000x reference)
//
#include <hip/hip_runtime.h>
#include <math.h>

// ---------------------------------------------------------------------------
// Bidirectional 2-layer LSTM (S=1024, B=64, IN=128, H=256) + linear head.
// Round 2: f32 compute, bf16 (raw ushort) workspace tensors.
//   Tier A (ws >= ~403MB): precompute Zx = x@W_ih^T + bias (bf16) in parallel;
//     recurrent kernel does only h@W_hh^T per step.
//   Tier B (ws >= ~135MB): recurrent kernel computes x-part on the fly.
//   Tier F (ws too small): fill d_out with ws_MB (informative failure).
// ---------------------------------------------------------------------------

typedef float f4 __attribute__((ext_vector_type(4)));
typedef unsigned short u16;

#define S_LEN 1024

__device__ __forceinline__ float sigf(float x) { return 1.0f / (1.0f + expf(-x)); }

__device__ __forceinline__ float b2f_raw(u16 u) {
  union { unsigned u; float f; } c;
  c.u = ((unsigned)u) << 16;
  return c.f;
}
__device__ __forceinline__ u16 f2b_raw(float f) {
  union { float f; unsigned u; } c;
  c.f = f;
  unsigned r = c.u + 0x7FFFu + ((c.u >> 16) & 1u);  // RNE
  return (u16)(r >> 16);
}

__device__ __forceinline__ f4 ld4(const float* p) { return *(const f4*)p; }
__device__ __forceinline__ f4 ld4(const u16* p) {
  ushort4 q = *(const ushort4*)p;
  f4 r;
  r[0] = b2f_raw(q.x); r[1] = b2f_raw(q.y);
  r[2] = b2f_raw(q.z); r[3] = b2f_raw(q.w);
  return r;
}
__device__ __forceinline__ void st4(float* p, f4 v) { *(f4*)p = v; }
__device__ __forceinline__ void st4(u16* p, f4 v) {
  ushort4 q;
  q.x = f2b_raw(v[0]); q.y = f2b_raw(v[1]);
  q.z = f2b_raw(v[2]); q.w = f2b_raw(v[3]);
  *(ushort4*)p = q;
}

// ---------------------------------------------------------------------------
__global__ void ws_probe(unsigned* p) {        // grid.x encodes ws MB (rocprof)
  if (blockIdx.x == 0x7FFFFFFFu) p[0] = 1u;    // never true
}
__global__ void fill_val(float* o, float v, unsigned n) {
  unsigned i = blockIdx.x * 256u + threadIdx.x;
  if (i < n) o[i] = v;
}
__global__ void init_sync(unsigned* __restrict__ sync) { sync[threadIdx.x] = 0u; }

// ---------------------------------------------------------------------------
// Per-direction global barrier (64 WGs per dir), all-poll on per-WG flags.
// ---------------------------------------------------------------------------
__device__ __forceinline__ void global_barrier(unsigned* sync, int d, int wg,
                                               unsigned ph, int tid) {
  if (tid < 256) __threadfence();
  __syncthreads();
  if (tid == 0)
    __hip_atomic_store(&sync[(d << 6) + wg], ph, __ATOMIC_RELEASE,
                       __HIP_MEMORY_SCOPE_AGENT);
  if (tid < 64) {
    while (__hip_atomic_load(&sync[(d << 6) + tid], __ATOMIC_ACQUIRE,
                             __HIP_MEMORY_SCOPE_AGENT) < ph) {
      __builtin_amdgcn_s_sleep(1);
    }
    __threadfence();
  }
  __syncthreads();
}

// ---------------------------------------------------------------------------
// Persistent recurrent kernel. 128 WGs = 2 dirs x 64 unit-groups (4 units),
// 512 threads. W_hh slice held in 128 VGPRs/lane for the whole launch.
// ---------------------------------------------------------------------------
template <int XMODE, typename TX>
__global__ __launch_bounds__(512, 2) void lstm_step(
    const u16* __restrict__ zx,   // [d][t*64+b][1024] bf16 (XMODE=0)
    const TX* __restrict__ xsrc, long sXb, long sXt, int Kx,   // (XMODE=1)
    const float* __restrict__ wih,  // [d][1024][Kx] (XMODE=1)
    const float* __restrict__ whh,  // [d][1024][256]
    const float* __restrict__ bih, const float* __restrict__ bhh,
    const float* __restrict__ h0, const float* __restrict__ c0, int l2,
    u16* __restrict__ y,            // [t][b][512] bf16, cols d*256+
    float* __restrict__ hglob,      // [2][2][256][64] f32
    unsigned* __restrict__ sync) {
  const int tid  = threadIdx.x;
  const int lane = tid & 63;
  const int ks   = tid >> 6;            // 0..7 K-split
  const int bg   = lane & 15, cg = lane >> 4;
  const int b4   = bg * 4,    cc4 = cg * 4;
  const int d    = blockIdx.x >> 6;
  const int wg   = blockIdx.x & 63;
  const int ub   = wg * 4;

  __shared__ float h_lds[256 * 64];             // [k][b] 64KB
  __shared__ float w_lds[256 * 16];             // staging only, 16KB
  __shared__ float zp[8 * 16 * 64];             // [ks][cc][b] 32KB
  __shared__ float xb[XMODE ? 64 * 64 : 4];     // [kx][b]
  __shared__ float wi[XMODE ? 64 * 16 : 4];     // [kx][cc]

  // Stage W_hh slice to LDS (then to registers after barrier).
  const float* whh_d = whh + (size_t)d * 1024 * 256;
  for (int idx = tid; idx < 256 * 16; idx += 512) {
    int k = idx & 255, cc = idx >> 8;
    int col = (cc >> 2) * 256 + ub + (cc & 3);
    w_lds[k * 16 + cc] = whh_d[(size_t)col * 256 + k];
  }

  const int gb = tid & 63, gu = (tid >> 6) & 3;
  float cst = 0.0f;
  float bias[4] = {0.f, 0.f, 0.f, 0.f};
  if (tid < 256) {
    int sidx = l2 + d;
    cst = c0[((size_t)sidx * 64 + gb) * 256 + ub + gu];
    float hinit = h0[((size_t)sidx * 64 + gb) * 256 + ub + gu];
    hglob[((size_t)(d * 2 + 0) * 256 + ub + gu) * 64 + gb] = hinit;
    if (XMODE) {
      for (int g = 0; g < 4; ++g) {
        int col = g * 256 + ub + gu;
        bias[g] = bih[d * 1024 + col] + bhh[d * 1024 + col];
      }
    }
  }
  unsigned ph = 1;
  global_barrier(sync, d, wg, ph++, tid);

  // W_hh K-slice into registers: wreg[kk] = w_lds[(ks*32+kk)][cc4..cc4+3].
  f4 wreg[32];
  {
    const int kbase = ks * 32;
#pragma unroll
    for (int kk = 0; kk < 32; ++kk)
      wreg[kk] = *(const f4*)(w_lds + (kbase + kk) * 16 + cc4);
  }

  const float* wih_d = XMODE ? (wih + (size_t)d * 1024 * (size_t)Kx) : nullptr;

  for (int t = 0; t < S_LEN; ++t) {
    const int p = t & 1;
    const int tdata = d ? (S_LEN - 1 - t) : t;

    // Stage this wave's K-slice of h (each wave reads only what it staged).
    {
      const float* hq = hglob + ((size_t)(d * 2 + p) * 256 + ks * 32) * 64;
      float* hl = h_lds + ks * 32 * 64;
#pragma unroll
      for (int it = 0; it < 8; ++it)
        *(f4*)(hl + it * 256 + lane * 4) = *(const f4*)(hq + it * 256 + lane * 4);
    }

    f4 acc0 = {0.f, 0.f, 0.f, 0.f}, acc1 = acc0, acc2 = acc0, acc3 = acc0;
    {
      const int kbase = ks * 32;
#pragma unroll
      for (int kk = 0; kk < 32; ++kk) {
        f4 hb = *(const f4*)(h_lds + (kbase + kk) * 64 + b4);
        f4 wv = wreg[kk];
        acc0 += hb * wv[0];
        acc1 += hb * wv[1];
        acc2 += hb * wv[2];
        acc3 += hb * wv[3];
      }
    }

    if (XMODE) {  // on-the-fly x-part, chunked through LDS
      const int nCh = Kx >> 6;
      for (int ch = 0; ch < nCh; ++ch) {
        __syncthreads();
        {
          const int bb = tid >> 3, kq = tid & 7;
          const TX* xs =
              xsrc + (size_t)bb * sXb + (size_t)tdata * sXt + ch * 64 + kq * 8;
          f4 v0 = ld4(xs);
          f4 v1 = ld4(xs + 4);
#pragma unroll
          for (int e = 0; e < 4; ++e) {
            xb[(kq * 8 + e) * 64 + bb] = v0[e];
            xb[(kq * 8 + 4 + e) * 64 + bb] = v1[e];
          }
        }
        for (int idx = tid; idx < 64 * 16; idx += 512) {
          int k = idx & 63, cc = idx >> 6;
          int col = (cc >> 2) * 256 + ub + (cc & 3);
          wi[k * 16 + cc] = wih_d[(size_t)col * Kx + ch * 64 + k];
        }
        __syncthreads();
        const int kxb = ks * 8;
#pragma unroll
        for (int kk = 0; kk < 8; ++kk) {
          int k = kxb + kk;
          f4 xv = *(const f4*)(xb + k * 64 + b4);
          f4 wv = *(const f4*)(wi + k * 16 + cc4);
          acc0 += xv * wv[0];
          acc1 += xv * wv[1];
          acc2 += xv * wv[2];
          acc3 += xv * wv[3];
        }
      }
    }

    *(f4*)(zp + ((ks * 16 + cc4 + 0) * 64 + b4)) = acc0;
    *(f4*)(zp + ((ks * 16 + cc4 + 1) * 64 + b4)) = acc1;
    *(f4*)(zp + ((ks * 16 + cc4 + 2) * 64 + b4)) = acc2;
    *(f4*)(zp + ((ks * 16 + cc4 + 3) * 64 + b4)) = acc3;
    __syncthreads();

    if (tid < 256) {
      float z[4];
#pragma unroll
      for (int g = 0; g < 4; ++g) {
        float s = 0.f;
#pragma unroll
        for (int q = 0; q < 8; ++q) s += zp[(q * 16 + g * 4 + gu) * 64 + gb];
        z[g] = s;
      }
      if (!XMODE) {
        const u16* zr =
            zx + ((size_t)d * S_LEN * 64 + (size_t)tdata * 64 + gb) * 1024;
#pragma unroll
        for (int g = 0; g < 4; ++g) z[g] += b2f_raw(zr[g * 256 + ub + gu]);
      } else {
#pragma unroll
        for (int g = 0; g < 4; ++g) z[g] += bias[g];
      }
      float iG = sigf(z[0]), fG = sigf(z[1]);
      float gG = tanhf(z[2]), oG = sigf(z[3]);
      cst = fG * cst + iG * gG;
      float hn = oG * tanhf(cst);
      hglob[((size_t)(d * 2 + (p ^ 1)) * 256 + ub + gu) * 64 + gb] = hn;
      y[((size_t)tdata * 64 + gb) * 512 + d * 256 + ub + gu] = f2b_raw(hn);
    }
    global_barrier(sync, d, wg, ph++, tid);
  }
}

// ---------------------------------------------------------------------------
// Tiled GEMM: C[d][m][n] = sum_k A(m,k)*B[d][n][k] + bias1[n] + bias2[n]
// A(m,k) = A[(m&63)*sAb + (m>>6)*sAt + k].  Tile 64x64, BK=32, 256 thr, 4x4.
// ---------------------------------------------------------------------------
template <typename TA, typename TC>
__global__ __launch_bounds__(256) void gemm_bias(
    const TA* __restrict__ A, long sAb, long sAt,
    const float* __restrict__ Bw, const float* __restrict__ bias1,
    const float* __restrict__ bias2, TC* __restrict__ C, int K, int N,
    long cDir, long biasDir, long bDir) {
  const int tid = threadIdx.x;
  const int nt = blockIdx.x, mt = blockIdx.y, d = blockIdx.z;
  const int tx = tid & 15, ty = tid >> 4;

  __shared__ float As[32 * 64];  // [k][m]
  __shared__ float Bs[32 * 64];  // [k][n]

  const float* Bd = Bw + (size_t)d * bDir;
  f4 zero = {0.f, 0.f, 0.f, 0.f};
  f4 acc[4] = {zero, zero, zero, zero};

  const int am = tid & 63, akq = tid >> 6;
  const long abase = (long)am * sAb + (long)mt * sAt;

  for (int kt = 0; kt < K; kt += 32) {
    {
      const TA* ap = A + abase + kt + akq * 8;
      f4 v0 = ld4(ap);
      f4 v1 = ld4(ap + 4);
#pragma unroll
      for (int e = 0; e < 4; ++e) {
        As[(akq * 8 + e) * 64 + am] = v0[e];
        As[(akq * 8 + 4 + e) * 64 + am] = v1[e];
      }
      const float* bp = Bd + (size_t)(nt * 64 + am) * K + kt + akq * 8;
      f4 w0 = *(const f4*)bp;
      f4 w1 = *(const f4*)(bp + 4);
#pragma unroll
      for (int e = 0; e < 4; ++e) {
        Bs[(akq * 8 + e) * 64 + am] = w0[e];
        Bs[(akq * 8 + 4 + e) * 64 + am] = w1[e];
      }
    }
    __syncthreads();
#pragma unroll 8
    for (int k = 0; k < 32; ++k) {
      f4 a = *(const f4*)(As + k * 64 + ty * 4);
      f4 b = *(const f4*)(Bs + k * 64 + tx * 4);
      acc[0] += b * a[0];
      acc[1] += b * a[1];
      acc[2] += b * a[2];
      acc[3] += b * a[3];
    }
    __syncthreads();
  }
  f4 bv = {0.f, 0.f, 0.f, 0.f};
  if (bias1) bv += *(const f4*)(bias1 + biasDir * d + nt * 64 + tx * 4);
  if (bias2) bv += *(const f4*)(bias2 + biasDir * d + nt * 64 + tx * 4);
  TC* Cp = C + (size_t)cDir * d + ((size_t)mt * 64 + ty * 4) * N + nt * 64 +
           tx * 4;
#pragma unroll
  for (int i = 0; i < 4; ++i) st4(Cp + (size_t)i * N, acc[i] + bv);
}

// ---------------------------------------------------------------------------
extern "C" void kernel_launch(void* const* d_in, const int* in_sizes, int n_in,
                              void* d_out, int out_size, void* d_ws,
                              size_t ws_size, hipStream_t stream) {
  const float* x    = (const float*)d_in[0];
  const float* h0   = (const float*)d_in[1];
  const float* c0   = (const float*)d_in[2];
  const float* wih0 = (const float*)d_in[3];
  const float* whh0 = (const float*)d_in[4];
  const float* bih0 = (const float*)d_in[5];
  const float* bhh0 = (const float*)d_in[6];
  const float* wih1 = (const float*)d_in[7];
  const float* whh1 = (const float*)d_in[8];
  const float* bih1 = (const float*)d_in[9];
  const float* bhh1 = (const float*)d_in[10];
  const float* linw = (const float*)d_in[11];
  const float* linb = (const float*)d_in[12];
  float* out = (float*)d_out;

  // ws probe: grid.x encodes ws size in MB (visible in rocprof on success).
  unsigned wsMB = (unsigned)(ws_size >> 20);
  ws_probe<<<dim3((wsMB < (1u << 20) ? wsMB : (1u << 20)) + 1u), 64, 0,
             stream>>>((unsigned*)d_out);

  const size_t M       = (size_t)S_LEN * 64;             // 65536
  const size_t Ybytes  = (size_t)S_LEN * 64 * 512 * 2;   // 67,108,864
  const size_t HGbytes = 2UL * 2 * 256 * 64 * 4;         // 524,288
  const size_t SYbytes = 1024;
  const size_t ZXbytes = 2UL * M * 1024 * 2;             // 268,435,456
  const size_t needB   = 2 * Ybytes + HGbytes + SYbytes; // 134,742,016
  const size_t needA   = needB + ZXbytes;                // 403,177,472

  if (ws_size < needB) {  // informative failure: absmax == ws MB
    fill_val<<<dim3(((unsigned)out_size + 255u) / 256u), 256, 0, stream>>>(
        out, (float)wsMB, (unsigned)out_size);
    return;
  }

  char* w = (char*)d_ws;
  u16* y0 = (u16*)w;              w += Ybytes;
  u16* y1 = (u16*)w;              w += Ybytes;
  float* hg = (float*)w;          w += HGbytes;
  unsigned* sync = (unsigned*)w;  w += SYbytes;
  u16* zx = (u16*)w;

  if (ws_size >= needA) {
    // Tier A: precompute Zx (bf16), recurrent kernel reads it.
    gemm_bias<float, u16><<<dim3(16, 1024, 2), 256, 0, stream>>>(
        x, (long)1024 * 128, 128, wih0, bih0, bhh0, zx, 128, 1024,
        (long)M * 1024, 1024, (long)1024 * 128);
    init_sync<<<1, 256, 0, stream>>>(sync);
    lstm_step<0, float><<<128, 512, 0, stream>>>(
        zx, nullptr, 0, 0, 0, nullptr, whh0, nullptr, nullptr, h0, c0, 0, y0,
        hg, sync);
    gemm_bias<u16, u16><<<dim3(16, 1024, 2), 256, 0, stream>>>(
        y0, 512, (long)64 * 512, wih1, bih1, bhh1, zx, 512, 1024,
        (long)M * 1024, 1024, (long)1024 * 512);
    init_sync<<<1, 256, 0, stream>>>(sync);
    lstm_step<0, float><<<128, 512, 0, stream>>>(
        zx, nullptr, 0, 0, 0, nullptr, whh1, nullptr, nullptr, h0, c0, 2, y1,
        hg, sync);
  } else {
    // Tier B: on-the-fly x-part.
    init_sync<<<1, 256, 0, stream>>>(sync);
    lstm_step<1, float><<<128, 512, 0, stream>>>(
        nullptr, x, (long)1024 * 128, 128, 128, wih0, whh0, bih0, bhh0, h0, c0,
        0, y0, hg, sync);
    init_sync<<<1, 256, 0, stream>>>(sync);
    lstm_step<1, u16><<<128, 512, 0, stream>>>(
        nullptr, y0, 512, (long)64 * 512, 512, wih1, whh1, bih1, bhh1, h0, c0,
        2, y1, hg, sync);
  }
  // Final linear: out = y1 @ lin_w^T + lin_b (f32 out).
  gemm_bias<u16, float><<<dim3(1, 1024, 1), 256, 0, stream>>>(
      y1, 512, (long)64 * 512, linw, linb, nullptr, out, 512, 64, 0, 0, 0);
}

// Round 3
// 130415.698 us; speedup vs baseline: 1.2702x; 1.2702x over previous
//
#include <hip/hip_runtime.h>
#include <math.h>

// ---------------------------------------------------------------------------
// Bidirectional 2-layer LSTM (S=1024, B=64, IN=128, H=256) + linear head.
// Round 3: same verified structure as round 2, but the cross-WG h exchange and
// barrier use RELAXED agent-scope atomics (LLC-coherent, no L2 invalidates).
// Round 2 failed mode: acquire-per-poll-iteration => full L2 invalidate per
// iteration => 54 GB fetch, 118 ms/dispatch. This round removes every
// acquire/release from the hot loop.
// ---------------------------------------------------------------------------

typedef float f4 __attribute__((ext_vector_type(4)));
typedef unsigned short u16;

#define S_LEN 1024

__device__ __forceinline__ float sigf(float x) { return 1.0f / (1.0f + expf(-x)); }

__device__ __forceinline__ float b2f_raw(u16 u) {
  union { unsigned u; float f; } c;
  c.u = ((unsigned)u) << 16;
  return c.f;
}
__device__ __forceinline__ u16 f2b_raw(float f) {
  union { float f; unsigned u; } c;
  c.f = f;
  unsigned r = c.u + 0x7FFFu + ((c.u >> 16) & 1u);  // RNE
  return (u16)(r >> 16);
}

__device__ __forceinline__ f4 ld4(const float* p) { return *(const f4*)p; }
__device__ __forceinline__ f4 ld4(const u16* p) {
  ushort4 q = *(const ushort4*)p;
  f4 r;
  r[0] = b2f_raw(q.x); r[1] = b2f_raw(q.y);
  r[2] = b2f_raw(q.z); r[3] = b2f_raw(q.w);
  return r;
}
__device__ __forceinline__ void st4(float* p, f4 v) { *(f4*)p = v; }
__device__ __forceinline__ void st4(u16* p, f4 v) {
  ushort4 q;
  q.x = f2b_raw(v[0]); q.y = f2b_raw(v[1]);
  q.z = f2b_raw(v[2]); q.w = f2b_raw(v[3]);
  *(ushort4*)p = q;
}

// Relaxed agent-scope accessors: served at the coherent point (LLC), bypassing
// the non-coherent per-XCD L2, WITHOUT any cache invalidate/writeback ops.
__device__ __forceinline__ float ld_llc(const float* p) {
  return __hip_atomic_load(p, __ATOMIC_RELAXED, __HIP_MEMORY_SCOPE_AGENT);
}
__device__ __forceinline__ void st_llc(float* p, float v) {
  __hip_atomic_store(p, v, __ATOMIC_RELAXED, __HIP_MEMORY_SCOPE_AGENT);
}
// Per-wave: drain this wave's outstanding vmem (stores reach coherence point).
__device__ __forceinline__ void wave_vm_drain() {
  asm volatile("s_waitcnt vmcnt(0)" ::: "memory");
}

// ---------------------------------------------------------------------------
__global__ void fill_val(float* o, float v, unsigned n) {
  unsigned i = blockIdx.x * 256u + threadIdx.x;
  if (i < n) o[i] = v;
}
__global__ void init_sync(unsigned* __restrict__ sync) { sync[threadIdx.x] = 0u; }

// ---------------------------------------------------------------------------
// Per-direction global barrier (64 WGs per dir), all-poll on per-WG flags.
// Release side: each h-storing wave drains its own stores (wave_vm_drain)
// before __syncthreads; then tid0 publishes the phase flag (relaxed, agent).
// Acquire side: relaxed polling (NO invalidates); reader's subsequent data
// loads are relaxed-agent (always fresh from LLC) and issue-ordered after the
// poll branch, so no fence is required.
// ---------------------------------------------------------------------------
__device__ __forceinline__ void global_barrier(unsigned* sync, int d, int wg,
                                               unsigned ph, int tid) {
  if (tid < 256) wave_vm_drain();
  __syncthreads();
  if (tid == 0)
    __hip_atomic_store(&sync[(d << 6) + wg], ph, __ATOMIC_RELAXED,
                       __HIP_MEMORY_SCOPE_AGENT);
  if (tid < 64) {
    while (__hip_atomic_load(&sync[(d << 6) + tid], __ATOMIC_RELAXED,
                             __HIP_MEMORY_SCOPE_AGENT) < ph) {
      __builtin_amdgcn_s_sleep(1);
    }
  }
  __syncthreads();
}

// ---------------------------------------------------------------------------
// Persistent recurrent kernel. 128 WGs = 2 dirs x 64 unit-groups (4 units),
// 512 threads. W_hh slice held in 128 VGPRs/lane for the whole launch.
// ---------------------------------------------------------------------------
template <int XMODE, typename TX>
__global__ __launch_bounds__(512, 2) void lstm_step(
    const u16* __restrict__ zx,   // [d][t*64+b][1024] bf16 (XMODE=0)
    const TX* __restrict__ xsrc, long sXb, long sXt, int Kx,   // (XMODE=1)
    const float* __restrict__ wih,  // [d][1024][Kx] (XMODE=1)
    const float* __restrict__ whh,  // [d][1024][256]
    const float* __restrict__ bih, const float* __restrict__ bhh,
    const float* __restrict__ h0, const float* __restrict__ c0, int l2,
    u16* __restrict__ y,            // [t][b][512] bf16, cols d*256+
    float* __restrict__ hglob,      // [2][2][256][64] f32, LLC-coherent
    unsigned* __restrict__ sync) {
  const int tid  = threadIdx.x;
  const int lane = tid & 63;
  const int ks   = tid >> 6;            // 0..7 K-split
  const int bg   = lane & 15, cg = lane >> 4;
  const int b4   = bg * 4,    cc4 = cg * 4;
  const int d    = blockIdx.x >> 6;
  const int wg   = blockIdx.x & 63;
  const int ub   = wg * 4;

  __shared__ float h_lds[256 * 64];             // [k][b] 64KB
  __shared__ float w_lds[256 * 16];             // staging only, 16KB
  __shared__ float zp[8 * 16 * 64];             // [ks][cc][b] 32KB
  __shared__ float xb[XMODE ? 64 * 64 : 4];     // [kx][b]
  __shared__ float wi[XMODE ? 64 * 16 : 4];     // [kx][cc]

  // Stage W_hh slice to LDS (then to registers after barrier).
  const float* whh_d = whh + (size_t)d * 1024 * 256;
  for (int idx = tid; idx < 256 * 16; idx += 512) {
    int k = idx & 255, cc = idx >> 8;
    int col = (cc >> 2) * 256 + ub + (cc & 3);
    w_lds[k * 16 + cc] = whh_d[(size_t)col * 256 + k];
  }

  const int gb = tid & 63, gu = (tid >> 6) & 3;
  float cst = 0.0f;
  float bias[4] = {0.f, 0.f, 0.f, 0.f};
  if (tid < 256) {
    int sidx = l2 + d;
    cst = c0[((size_t)sidx * 64 + gb) * 256 + ub + gu];
    float hinit = h0[((size_t)sidx * 64 + gb) * 256 + ub + gu];
    st_llc(&hglob[((size_t)(d * 2 + 0) * 256 + ub + gu) * 64 + gb], hinit);
    if (XMODE) {
      for (int g = 0; g < 4; ++g) {
        int col = g * 256 + ub + gu;
        bias[g] = bih[d * 1024 + col] + bhh[d * 1024 + col];
      }
    }
  }
  unsigned ph = 1;
  global_barrier(sync, d, wg, ph++, tid);

  // W_hh K-slice into registers: wreg[kk] = w_lds[(ks*32+kk)][cc4..cc4+3].
  f4 wreg[32];
  {
    const int kbase = ks * 32;
#pragma unroll
    for (int kk = 0; kk < 32; ++kk)
      wreg[kk] = *(const f4*)(w_lds + (kbase + kk) * 16 + cc4);
  }

  const float* wih_d = XMODE ? (wih + (size_t)d * 1024 * (size_t)Kx) : nullptr;

  for (int t = 0; t < S_LEN; ++t) {
    const int p = t & 1;
    const int tdata = d ? (S_LEN - 1 - t) : t;

    // Stage this wave's K-slice of h from LLC (relaxed agent atomics; each
    // wave reads only the rows it staged, so no extra block sync needed).
    {
      const float* hq = hglob + ((size_t)(d * 2 + p) * 256 + ks * 32) * 64;
      float* hl = h_lds + ks * 32 * 64;
#pragma unroll
      for (int it = 0; it < 8; ++it) {
        const int off = it * 256 + lane * 4;
        f4 v;
        v[0] = ld_llc(hq + off + 0);
        v[1] = ld_llc(hq + off + 1);
        v[2] = ld_llc(hq + off + 2);
        v[3] = ld_llc(hq + off + 3);
        *(f4*)(hl + off) = v;
      }
    }

    f4 acc0 = {0.f, 0.f, 0.f, 0.f}, acc1 = acc0, acc2 = acc0, acc3 = acc0;
    {
      const int kbase = ks * 32;
#pragma unroll
      for (int kk = 0; kk < 32; ++kk) {
        f4 hb = *(const f4*)(h_lds + (kbase + kk) * 64 + b4);
        f4 wv = wreg[kk];
        acc0 += hb * wv[0];
        acc1 += hb * wv[1];
        acc2 += hb * wv[2];
        acc3 += hb * wv[3];
      }
    }

    if (XMODE) {  // on-the-fly x-part, chunked through LDS
      const int nCh = Kx >> 6;
      for (int ch = 0; ch < nCh; ++ch) {
        __syncthreads();
        {
          const int bb = tid >> 3, kq = tid & 7;
          const TX* xs =
              xsrc + (size_t)bb * sXb + (size_t)tdata * sXt + ch * 64 + kq * 8;
          f4 v0 = ld4(xs);
          f4 v1 = ld4(xs + 4);
#pragma unroll
          for (int e = 0; e < 4; ++e) {
            xb[(kq * 8 + e) * 64 + bb] = v0[e];
            xb[(kq * 8 + 4 + e) * 64 + bb] = v1[e];
          }
        }
        for (int idx = tid; idx < 64 * 16; idx += 512) {
          int k = idx & 63, cc = idx >> 6;
          int col = (cc >> 2) * 256 + ub + (cc & 3);
          wi[k * 16 + cc] = wih_d[(size_t)col * Kx + ch * 64 + k];
        }
        __syncthreads();
        const int kxb = ks * 8;
#pragma unroll
        for (int kk = 0; kk < 8; ++kk) {
          int k = kxb + kk;
          f4 xv = *(const f4*)(xb + k * 64 + b4);
          f4 wv = *(const f4*)(wi + k * 16 + cc4);
          acc0 += xv * wv[0];
          acc1 += xv * wv[1];
          acc2 += xv * wv[2];
          acc3 += xv * wv[3];
        }
      }
    }

    *(f4*)(zp + ((ks * 16 + cc4 + 0) * 64 + b4)) = acc0;
    *(f4*)(zp + ((ks * 16 + cc4 + 1) * 64 + b4)) = acc1;
    *(f4*)(zp + ((ks * 16 + cc4 + 2) * 64 + b4)) = acc2;
    *(f4*)(zp + ((ks * 16 + cc4 + 3) * 64 + b4)) = acc3;
    __syncthreads();

    if (tid < 256) {
      float z[4];
#pragma unroll
      for (int g = 0; g < 4; ++g) {
        float s = 0.f;
#pragma unroll
        for (int q = 0; q < 8; ++q) s += zp[(q * 16 + g * 4 + gu) * 64 + gb];
        z[g] = s;
      }
      if (!XMODE) {
        const u16* zr =
            zx + ((size_t)d * S_LEN * 64 + (size_t)tdata * 64 + gb) * 1024;
#pragma unroll
        for (int g = 0; g < 4; ++g) z[g] += b2f_raw(zr[g * 256 + ub + gu]);
      } else {
#pragma unroll
        for (int g = 0; g < 4; ++g) z[g] += bias[g];
      }
      float iG = sigf(z[0]), fG = sigf(z[1]);
      float gG = tanhf(z[2]), oG = sigf(z[3]);
      cst = fG * cst + iG * gG;
      float hn = oG * tanhf(cst);
      st_llc(&hglob[((size_t)(d * 2 + (p ^ 1)) * 256 + ub + gu) * 64 + gb], hn);
      y[((size_t)tdata * 64 + gb) * 512 + d * 256 + ub + gu] = f2b_raw(hn);
    }
    global_barrier(sync, d, wg, ph++, tid);
  }
}

// ---------------------------------------------------------------------------
// Tiled GEMM: C[d][m][n] = sum_k A(m,k)*B[d][n][k] + bias1[n] + bias2[n]
// A(m,k) = A[(m&63)*sAb + (m>>6)*sAt + k].  Tile 64x64, BK=32, 256 thr, 4x4.
// ---------------------------------------------------------------------------
template <typename TA, typename TC>
__global__ __launch_bounds__(256) void gemm_bias(
    const TA* __restrict__ A, long sAb, long sAt,
    const float* __restrict__ Bw, const float* __restrict__ bias1,
    const float* __restrict__ bias2, TC* __restrict__ C, int K, int N,
    long cDir, long biasDir, long bDir) {
  const int tid = threadIdx.x;
  const int nt = blockIdx.x, mt = blockIdx.y, d = blockIdx.z;
  const int tx = tid & 15, ty = tid >> 4;

  __shared__ float As[32 * 64];  // [k][m]
  __shared__ float Bs[32 * 64];  // [k][n]

  const float* Bd = Bw + (size_t)d * bDir;
  f4 zero = {0.f, 0.f, 0.f, 0.f};
  f4 acc[4] = {zero, zero, zero, zero};

  const int am = tid & 63, akq = tid >> 6;
  const long abase = (long)am * sAb + (long)mt * sAt;

  for (int kt = 0; kt < K; kt += 32) {
    {
      const TA* ap = A + abase + kt + akq * 8;
      f4 v0 = ld4(ap);
      f4 v1 = ld4(ap + 4);
#pragma unroll
      for (int e = 0; e < 4; ++e) {
        As[(akq * 8 + e) * 64 + am] = v0[e];
        As[(akq * 8 + 4 + e) * 64 + am] = v1[e];
      }
      const float* bp = Bd + (size_t)(nt * 64 + am) * K + kt + akq * 8;
      f4 w0 = *(const f4*)bp;
      f4 w1 = *(const f4*)(bp + 4);
#pragma unroll
      for (int e = 0; e < 4; ++e) {
        Bs[(akq * 8 + e) * 64 + am] = w0[e];
        Bs[(akq * 8 + 4 + e) * 64 + am] = w1[e];
      }
    }
    __syncthreads();
#pragma unroll 8
    for (int k = 0; k < 32; ++k) {
      f4 a = *(const f4*)(As + k * 64 + ty * 4);
      f4 b = *(const f4*)(Bs + k * 64 + tx * 4);
      acc[0] += b * a[0];
      acc[1] += b * a[1];
      acc[2] += b * a[2];
      acc[3] += b * a[3];
    }
    __syncthreads();
  }
  f4 bv = {0.f, 0.f, 0.f, 0.f};
  if (bias1) bv += *(const f4*)(bias1 + biasDir * d + nt * 64 + tx * 4);
  if (bias2) bv += *(const f4*)(bias2 + biasDir * d + nt * 64 + tx * 4);
  TC* Cp = C + (size_t)cDir * d + ((size_t)mt * 64 + ty * 4) * N + nt * 64 +
           tx * 4;
#pragma unroll
  for (int i = 0; i < 4; ++i) st4(Cp + (size_t)i * N, acc[i] + bv);
}

// ---------------------------------------------------------------------------
extern "C" void kernel_launch(void* const* d_in, const int* in_sizes, int n_in,
                              void* d_out, int out_size, void* d_ws,
                              size_t ws_size, hipStream_t stream) {
  const float* x    = (const float*)d_in[0];
  const float* h0   = (const float*)d_in[1];
  const float* c0   = (const float*)d_in[2];
  const float* wih0 = (const float*)d_in[3];
  const float* whh0 = (const float*)d_in[4];
  const float* bih0 = (const float*)d_in[5];
  const float* bhh0 = (const float*)d_in[6];
  const float* wih1 = (const float*)d_in[7];
  const float* whh1 = (const float*)d_in[8];
  const float* bih1 = (const float*)d_in[9];
  const float* bhh1 = (const float*)d_in[10];
  const float* linw = (const float*)d_in[11];
  const float* linb = (const float*)d_in[12];
  float* out = (float*)d_out;

  const size_t M       = (size_t)S_LEN * 64;             // 65536
  const size_t Ybytes  = (size_t)S_LEN * 64 * 512 * 2;   // 67,108,864
  const size_t HGbytes = 2UL * 2 * 256 * 64 * 4;         // 524,288
  const size_t SYbytes = 1024;
  const size_t ZXbytes = 2UL * M * 1024 * 2;             // 268,435,456
  const size_t needB   = 2 * Ybytes + HGbytes + SYbytes; // 134,742,016
  const size_t needA   = needB + ZXbytes;                // 403,177,472

  if (ws_size < needB) {  // informative failure: absmax == ws MB
    fill_val<<<dim3(((unsigned)out_size + 255u) / 256u), 256, 0, stream>>>(
        out, (float)(unsigned)(ws_size >> 20), (unsigned)out_size);
    return;
  }

  char* w = (char*)d_ws;
  u16* y0 = (u16*)w;              w += Ybytes;
  u16* y1 = (u16*)w;              w += Ybytes;
  float* hg = (float*)w;          w += HGbytes;
  unsigned* sync = (unsigned*)w;  w += SYbytes;
  u16* zx = (u16*)w;

  if (ws_size >= needA) {
    // Tier A: precompute Zx (bf16), recurrent kernel reads it.
    gemm_bias<float, u16><<<dim3(16, 1024, 2), 256, 0, stream>>>(
        x, (long)1024 * 128, 128, wih0, bih0, bhh0, zx, 128, 1024,
        (long)M * 1024, 1024, (long)1024 * 128);
    init_sync<<<1, 256, 0, stream>>>(sync);
    lstm_step<0, float><<<128, 512, 0, stream>>>(
        zx, nullptr, 0, 0, 0, nullptr, whh0, nullptr, nullptr, h0, c0, 0, y0,
        hg, sync);
    gemm_bias<u16, u16><<<dim3(16, 1024, 2), 256, 0, stream>>>(
        y0, 512, (long)64 * 512, wih1, bih1, bhh1, zx, 512, 1024,
        (long)M * 1024, 1024, (long)1024 * 512);
    init_sync<<<1, 256, 0, stream>>>(sync);
    lstm_step<0, float><<<128, 512, 0, stream>>>(
        zx, nullptr, 0, 0, 0, nullptr, whh1, nullptr, nullptr, h0, c0, 2, y1,
        hg, sync);
  } else {
    // Tier B: on-the-fly x-part.
    init_sync<<<1, 256, 0, stream>>>(sync);
    lstm_step<1, float><<<128, 512, 0, stream>>>(
        nullptr, x, (long)1024 * 128, 128, 128, wih0, whh0, bih0, bhh0, h0, c0,
        0, y0, hg, sync);
    init_sync<<<1, 256, 0, stream>>>(sync);
    lstm_step<1, u16><<<128, 512, 0, stream>>>(
        nullptr, y0, 512, (long)64 * 512, 512, wih1, whh1, bih1, bhh1, h0, c0,
        2, y1, hg, sync);
  }
  // Final linear: out = y1 @ lin_w^T + lin_b (f32 out).
  gemm_bias<u16, float><<<dim3(1, 1024, 1), 256, 0, stream>>>(
      y1, 512, (long)64 * 512, linw, linb, nullptr, out, 512, 64, 0, 0, 0);
}